// Round 1
// baseline (348.842 us; speedup 1.0000x reference)
//
#include <hip/hip_runtime.h>

// ---------------------------------------------------------------------------
// MH-MoE: out = merge( MoE( heads(x @ W_mh + b_mh) ) ) @ W_merge + b_merge
// B=2 S=2048 H=1024 NH=8 HD=128 T=16384 (B*T=32768 tokens) E=8 K=2 F=512
// All GEMMs in bf16 MFMA (16x16x32), fp32 accum. Router logits in exact fp32
// via Wcomb = W_mh @ W_router to keep top-2 selection identical to reference.
// ---------------------------------------------------------------------------

typedef __attribute__((ext_vector_type(8))) short bf16x8;
typedef __attribute__((ext_vector_type(4))) float f32x4;
typedef __attribute__((ext_vector_type(4))) unsigned short u16x4;

__device__ __forceinline__ unsigned short f2bf(float x) {
  unsigned int u = __float_as_uint(x);
  return (unsigned short)((u + 0x7FFFu + ((u >> 16) & 1u)) >> 16);
}

__device__ __forceinline__ void gload_lds16(const void* g, void* l) {
  __builtin_amdgcn_global_load_lds(
      (const __attribute__((address_space(1))) unsigned int*)g,
      (__attribute__((address_space(3))) unsigned int*)l, 16, 0, 0);
}

// ---------------- cast x -> bf16 ----------------
__global__ __launch_bounds__(256) void cast_f32_to_bf16(
    const float* __restrict__ src, unsigned short* __restrict__ dst, int n4) {
  int i = blockIdx.x * blockDim.x + threadIdx.x;
  int stride = gridDim.x * blockDim.x;
  for (; i < n4; i += stride) {
    float4 v = ((const float4*)src)[i];
    u16x4 o;
    o.x = f2bf(v.x); o.y = f2bf(v.y); o.z = f2bf(v.z); o.w = f2bf(v.w);
    ((u16x4*)dst)[i] = o;
  }
}

// ---------------- transpose + cast: src[R][C] f32 -> dst[C][R] bf16 --------
// grid (C/32, R/32, batch), block (32,8)
__global__ __launch_bounds__(256) void transpose_cast(
    const float* __restrict__ src, unsigned short* __restrict__ dst,
    int R, int C) {
  __shared__ float tile[32][33];
  size_t base = (size_t)blockIdx.z * R * C;
  int c0 = blockIdx.x * 32, r0 = blockIdx.y * 32;
  for (int i = threadIdx.y; i < 32; i += 8)
    tile[i][threadIdx.x] = src[base + (size_t)(r0 + i) * C + c0 + threadIdx.x];
  __syncthreads();
  for (int i = threadIdx.y; i < 32; i += 8)
    dst[base + (size_t)(c0 + i) * R + r0 + threadIdx.x] = f2bf(tile[threadIdx.x][i]);
}

// ---------------- Wcomb[r][nh*8+e] = sum_d W_mh[r][nh*128+d] * Wr[d][e] ----
// grid 1025 (row 1024 = b_mh row -> bias-combined), block 64
__global__ __launch_bounds__(64) void wcomb_kernel(
    const float* __restrict__ Wmh, const float* __restrict__ bmh,
    const float* __restrict__ Wr, float* __restrict__ Wc) {
  int r = blockIdx.x;
  const float* src = (r < 1024) ? (Wmh + (size_t)r * 1024) : bmh;
  int nh = threadIdx.x >> 3, e = threadIdx.x & 7;
  float acc = 0.f;
  for (int d = 0; d < 128; ++d) acc = fmaf(src[nh * 128 + d], Wr[d * 8 + e], acc);
  Wc[(size_t)r * 64 + threadIdx.x] = acc;
}

// ---------------- router: logits = x @ Wc (+bias row), top-2 gates --------
// grid 512 (8 x-rows each), block 256
__global__ __launch_bounds__(256) void router_kernel(
    const float* __restrict__ x, const float* __restrict__ Wc,
    float* __restrict__ gates) {
  __shared__ float xs[8 * 1024];
  __shared__ float lg[8][64];
  int r0 = blockIdx.x * 8;
  const float4* xg = (const float4*)(x + (size_t)r0 * 1024);
  float4* xs4 = (float4*)xs;
  for (int i = threadIdx.x; i < 2048; i += 256) xs4[i] = xg[i];
  __syncthreads();
  int g = threadIdx.x >> 6, lane = threadIdx.x & 63;
  float a0 = Wc[1024 * 64 + lane], a1 = a0;  // bias-combined row
  const float* x0 = xs + g * 1024;
  const float* x1 = xs + (g + 4) * 1024;
  for (int k = 0; k < 1024; ++k) {
    float w = Wc[(size_t)k * 64 + lane];
    a0 = fmaf(x0[k], w, a0);
    a1 = fmaf(x1[k], w, a1);
  }
  lg[g][lane] = a0; lg[g + 4][lane] = a1;
  __syncthreads();
  if (threadIdx.x < 64) {
    int row = threadIdx.x >> 3, nh = threadIdx.x & 7;
    float l[8];
#pragma unroll
    for (int e = 0; e < 8; ++e) l[e] = lg[row][nh * 8 + e];
    int i1 = 0; float v1 = l[0];
#pragma unroll
    for (int e = 1; e < 8; ++e) if (l[e] > v1) { v1 = l[e]; i1 = e; }
    int i2 = -1; float v2 = -1e30f;
#pragma unroll
    for (int e = 0; e < 8; ++e) if (e != i1 && l[e] > v2) { v2 = l[e]; i2 = e; }
    // softmax-then-renormalized-top2 == softmax over the top-2 logits
    float g1 = 1.f / (1.f + __expf(v2 - v1));
    float g2 = 1.f - g1;
    size_t t = (size_t)(r0 + row) * 8 + nh;
    float o[8];
#pragma unroll
    for (int e = 0; e < 8; ++e) o[e] = 0.f;
    o[i1] = g1; o[i2] = g2;
#pragma unroll
    for (int e = 0; e < 8; ++e) gates[t * 8 + e] = o[e];
  }
}

// ---------------- GEMM: C[M][N] = A[M][K](bf16) @ Bt[N][K](bf16)^T + bias --
// 128x128 tile, BK=64, 4 waves (2x2), global_load_lds, 2-phase double buffer
template <int OUT_BF16>
__global__ __launch_bounds__(256) void gemm_bt(
    const unsigned short* __restrict__ A, const unsigned short* __restrict__ Bt,
    const float* __restrict__ bias, void* __restrict__ Cout,
    int M, int N, int K) {
  __shared__ unsigned short As[2][128 * 64];
  __shared__ unsigned short Bs[2][128 * 64];
  const int tid = threadIdx.x, lane = tid & 63, wid = tid >> 6;
  const int wr = wid >> 1, wc = wid & 1;
  const int m0 = blockIdx.y * 128, n0 = blockIdx.x * 128;
  const int l15 = lane & 15, lhi = lane >> 4;

  f32x4 acc[4][4];
#pragma unroll
  for (int n = 0; n < 4; ++n) {
    float bv = bias[n0 + wc * 64 + n * 16 + l15];
#pragma unroll
    for (int m = 0; m < 4; ++m) acc[m][n] = (f32x4){bv, bv, bv, bv};
  }

  const int rowi = tid >> 3;       // 0..31 (row within 32-row round)
  const int segi = (tid & 7) * 8;  // k element offset
  const int NT = K >> 6;

  auto stage = [&](int buf, int kt) {
    const int k0 = kt * 64;
#pragma unroll
    for (int r = 0; r < 4; ++r) {
      gload_lds16(A + (size_t)(m0 + r * 32 + rowi) * K + k0 + segi,
                  &As[buf][r * 2048 + wid * 512]);
      gload_lds16(Bt + (size_t)(n0 + r * 32 + rowi) * K + k0 + segi,
                  &Bs[buf][r * 2048 + wid * 512]);
    }
  };

  stage(0, 0);
  asm volatile("s_waitcnt vmcnt(0)" ::: "memory");
  __syncthreads();
  int cur = 0;
  for (int t = 0; t < NT; ++t) {
    if (t + 1 < NT) stage(cur ^ 1, t + 1);
#pragma unroll
    for (int ks = 0; ks < 64; ks += 32) {
      bf16x8 af[4], bb[4];
#pragma unroll
      for (int m = 0; m < 4; ++m)
        af[m] = *(const bf16x8*)&As[cur][(wr * 64 + m * 16 + l15) * 64 + ks + lhi * 8];
#pragma unroll
      for (int n = 0; n < 4; ++n)
        bb[n] = *(const bf16x8*)&Bs[cur][(wc * 64 + n * 16 + l15) * 64 + ks + lhi * 8];
#pragma unroll
      for (int m = 0; m < 4; ++m)
#pragma unroll
        for (int n = 0; n < 4; ++n)
          acc[m][n] = __builtin_amdgcn_mfma_f32_16x16x32_bf16(af[m], bb[n], acc[m][n], 0, 0, 0);
    }
    asm volatile("s_waitcnt vmcnt(0)" ::: "memory");
    __syncthreads();
    cur ^= 1;
  }
#pragma unroll
  for (int m = 0; m < 4; ++m) {
#pragma unroll
    for (int n = 0; n < 4; ++n) {
      int col = n0 + wc * 64 + n * 16 + l15;
#pragma unroll
      for (int j = 0; j < 4; ++j) {
        int row = m0 + wr * 64 + m * 16 + lhi * 4 + j;
        if (OUT_BF16)
          ((unsigned short*)Cout)[(size_t)row * N + col] = f2bf(acc[m][n][j]);
        else
          ((float*)Cout)[(size_t)row * N + col] = acc[m][n][j];
      }
    }
  }
}

// ---------------- fused MoE FFN (dense over experts, gates folded in) ------
// per block: 128 tokens; 8 waves (2 row-halves x 4 col-quarters)
// for each (expert, F-chunk of 128): act=gelu(h@W1+b1)*gate -> LDS(bf16) ->
// y += act@W2 ; epilogue adds sum_e gate*b2 and writes moe bf16.
__global__ __launch_bounds__(512) void moe_ffn_kernel(
    const unsigned short* __restrict__ hbf,   // [32768][128]
    const float* __restrict__ gates,          // [32768][8]
    const unsigned short* __restrict__ W1t,   // [8][512][128] (f, hd)
    const float* __restrict__ b1,             // [8][512]
    const unsigned short* __restrict__ W2t,   // [8][128][512] (hd, f)
    const float* __restrict__ b2,             // [8][128]
    unsigned short* __restrict__ moebf) {     // [32768][128]
  __shared__ unsigned short h_s[128][136];   // +8 pad: bank-spread, 16B aligned
  __shared__ unsigned short act_s[128][136];
  __shared__ float gate_s[128][8];
  __shared__ float b2_s[8 * 128];
  const int tid = threadIdx.x, lane = tid & 63, wid = tid >> 6;
  const int wr = wid >> 2, wc = wid & 3;  // wr in {0,1}: 64 rows; wc in 0..3: 32 cols
  const int l15 = lane & 15, lhi = lane >> 4;
  const int t0 = blockIdx.x * 128;

  for (int s = tid; s < 128 * 16; s += 512) {
    int row = s >> 4, seg = (s & 15) * 8;
    bf16x8 v = *(const bf16x8*)(hbf + (size_t)(t0 + row) * 128 + seg);
    *(bf16x8*)&h_s[row][seg] = v;
  }
  for (int i = tid; i < 128 * 8; i += 512)
    gate_s[i >> 3][i & 7] = gates[(size_t)(t0 + (i >> 3)) * 8 + (i & 7)];
  for (int i = tid; i < 1024; i += 512) b2_s[i] = b2[i];
  __syncthreads();

  f32x4 yacc[4][2];
#pragma unroll
  for (int m = 0; m < 4; ++m)
#pragma unroll
    for (int n = 0; n < 2; ++n) yacc[m][n] = (f32x4){0.f, 0.f, 0.f, 0.f};

  for (int e = 0; e < 8; ++e) {
    for (int fc = 0; fc < 4; ++fc) {
      f32x4 aacc[4][2];
#pragma unroll
      for (int m = 0; m < 4; ++m)
#pragma unroll
        for (int n = 0; n < 2; ++n) aacc[m][n] = (f32x4){0.f, 0.f, 0.f, 0.f};

      const unsigned short* W1p = W1t + ((size_t)e * 512 + fc * 128) * 128;
#pragma unroll
      for (int ks = 0; ks < 128; ks += 32) {
        bf16x8 af[4], bb[2];
#pragma unroll
        for (int m = 0; m < 4; ++m)
          af[m] = *(const bf16x8*)&h_s[wr * 64 + m * 16 + l15][ks + lhi * 8];
#pragma unroll
        for (int n = 0; n < 2; ++n)
          bb[n] = *(const bf16x8*)(W1p + (size_t)(wc * 32 + n * 16 + l15) * 128 + ks + lhi * 8);
#pragma unroll
        for (int m = 0; m < 4; ++m)
#pragma unroll
          for (int n = 0; n < 2; ++n)
            aacc[m][n] = __builtin_amdgcn_mfma_f32_16x16x32_bf16(af[m], bb[n], aacc[m][n], 0, 0, 0);
      }
      __syncthreads();  // previous chunk's act_s reads complete
#pragma unroll
      for (int n = 0; n < 2; ++n) {
        int fl = wc * 32 + n * 16 + l15;
        float b1v = b1[(size_t)e * 512 + fc * 128 + fl];
#pragma unroll
        for (int m = 0; m < 4; ++m) {
#pragma unroll
          for (int j = 0; j < 4; ++j) {
            int row = wr * 64 + m * 16 + lhi * 4 + j;
            float v = aacc[m][n][j] + b1v;
            // jax.nn.gelu approximate=True (tanh form)
            float u = 0.7978845608028654f * (v + 0.044715f * v * v * v);
            float ex = __expf(2.f * u);
            float th = 1.f - 2.f / (ex + 1.f);
            float ge = 0.5f * v * (1.f + th);
            act_s[row][fl] = f2bf(ge * gate_s[row][e]);
          }
        }
      }
      __syncthreads();  // act_s visible
      const unsigned short* W2p = W2t + (size_t)e * 128 * 512 + fc * 128;
#pragma unroll
      for (int ks = 0; ks < 128; ks += 32) {
        bf16x8 af[4], bb[2];
#pragma unroll
        for (int m = 0; m < 4; ++m)
          af[m] = *(const bf16x8*)&act_s[wr * 64 + m * 16 + l15][ks + lhi * 8];
#pragma unroll
        for (int n = 0; n < 2; ++n)
          bb[n] = *(const bf16x8*)(W2p + (size_t)(wc * 32 + n * 16 + l15) * 512 + ks + lhi * 8);
#pragma unroll
        for (int m = 0; m < 4; ++m)
#pragma unroll
          for (int n = 0; n < 2; ++n)
            yacc[m][n] = __builtin_amdgcn_mfma_f32_16x16x32_bf16(af[m], bb[n], yacc[m][n], 0, 0, 0);
      }
    }
  }
#pragma unroll
  for (int n = 0; n < 2; ++n) {
    int col = wc * 32 + n * 16 + l15;
#pragma unroll
    for (int m = 0; m < 4; ++m) {
#pragma unroll
      for (int j = 0; j < 4; ++j) {
        int row = wr * 64 + m * 16 + lhi * 4 + j;
        float s = yacc[m][n][j];
#pragma unroll
        for (int e = 0; e < 8; ++e) s += gate_s[row][e] * b2_s[e * 128 + col];
        moebf[(size_t)(t0 + row) * 128 + col] = f2bf(s);
      }
    }
  }
}

// ---------------------------------------------------------------------------
extern "C" void kernel_launch(void* const* d_in, const int* in_sizes, int n_in,
                              void* d_out, int out_size, void* d_ws, size_t ws_size,
                              hipStream_t stream) {
  const float* x       = (const float*)d_in[0];
  const float* W_mh    = (const float*)d_in[1];
  const float* b_mh    = (const float*)d_in[2];
  const float* W_merge = (const float*)d_in[3];
  const float* b_merge = (const float*)d_in[4];
  const float* W_rout  = (const float*)d_in[5];
  const float* W1      = (const float*)d_in[6];
  const float* b1      = (const float*)d_in[7];
  const float* W2      = (const float*)d_in[8];
  const float* b2      = (const float*)d_in[9];
  float* out = (float*)d_out;

  char* ws = (char*)d_ws;
  size_t off = 0;
  auto alloc = [&](size_t bytes) {
    void* p = ws + off;
    off = (off + bytes + 255) & ~(size_t)255;
    return p;
  };
  unsigned short* x_bf  = (unsigned short*)alloc((size_t)4096 * 1024 * 2);
  unsigned short* Wmh_t = (unsigned short*)alloc((size_t)1024 * 1024 * 2);
  unsigned short* Wmg_t = (unsigned short*)alloc((size_t)1024 * 1024 * 2);
  unsigned short* W1t   = (unsigned short*)alloc((size_t)8 * 512 * 128 * 2);
  unsigned short* W2t   = (unsigned short*)alloc((size_t)8 * 512 * 128 * 2);
  unsigned short* h_bf  = (unsigned short*)alloc((size_t)4096 * 1024 * 2);
  unsigned short* moebf = (unsigned short*)alloc((size_t)4096 * 1024 * 2);
  float* gates          = (float*)alloc((size_t)32768 * 8 * 4);
  float* Wc             = (float*)alloc((size_t)1025 * 64 * 4);

  cast_f32_to_bf16<<<1024, 256, 0, stream>>>(x, x_bf, 4096 * 1024 / 4);
  transpose_cast<<<dim3(32, 32, 1), dim3(32, 8), 0, stream>>>(W_mh, Wmh_t, 1024, 1024);
  transpose_cast<<<dim3(32, 32, 1), dim3(32, 8), 0, stream>>>(W_merge, Wmg_t, 1024, 1024);
  transpose_cast<<<dim3(16, 4, 8), dim3(32, 8), 0, stream>>>(W1, W1t, 128, 512);
  transpose_cast<<<dim3(4, 16, 8), dim3(32, 8), 0, stream>>>(W2, W2t, 512, 128);
  wcomb_kernel<<<1025, 64, 0, stream>>>(W_mh, b_mh, W_rout, Wc);
  router_kernel<<<512, 256, 0, stream>>>(x, Wc, gates);
  gemm_bt<1><<<dim3(8, 32), 256, 0, stream>>>(x_bf, Wmh_t, b_mh, (void*)h_bf, 4096, 1024, 1024);
  moe_ffn_kernel<<<256, 512, 0, stream>>>(h_bf, gates, W1t, b1, W2t, b2, moebf);
  gemm_bt<0><<<dim3(8, 32), 256, 0, stream>>>(moebf, Wmg_t, b_merge, (void*)out, 4096, 1024, 1024);
}

// Round 2
// 223.652 us; speedup vs baseline: 1.5598x; 1.5598x over previous
//
#include <hip/hip_runtime.h>

// ---------------------------------------------------------------------------
// MH-MoE with top-2 sparse expert dispatch.
// B=2 S=2048 H=1024 NH=8 HD=128 T=16384 (32768 tokens) E=8 K=2 F=512
// Pipeline: cast/transpose prep -> router (exact fp32 logits via
// Wc = W_mh@W_router) -> scan -> assign (token->slot permutation) ->
// GEMM1 (x@W_mh) -> sparse FFN over gathered tiles -> combine -> GEMM2.
// ---------------------------------------------------------------------------

typedef __attribute__((ext_vector_type(8))) short bf16x8;
typedef __attribute__((ext_vector_type(4))) float f32x4;
typedef __attribute__((ext_vector_type(4))) unsigned short u16x4;

constexpr int NSLOT = 66560;      // 520 tiles * 128 slots (65536 + pad)
constexpr int NTILE_MAX = 520;
// ctrl layout (ints): [0..7] counts, [8..15] cursors, [16..24] offsets, [32..] tile_e
#define CTRL_CNT 0
#define CTRL_CUR 8
#define CTRL_OFF 16
#define CTRL_TILE 32

__device__ __forceinline__ unsigned short f2bf(float x) {
  unsigned int u = __float_as_uint(x);
  return (unsigned short)((u + 0x7FFFu + ((u >> 16) & 1u)) >> 16);
}
__device__ __forceinline__ float bf2f(unsigned short u) {
  return __uint_as_float(((unsigned int)u) << 16);
}
__device__ __forceinline__ void gload_lds16(const void* g, void* l) {
  __builtin_amdgcn_global_load_lds(
      (const __attribute__((address_space(1))) unsigned int*)g,
      (__attribute__((address_space(3))) unsigned int*)l, 16, 0, 0);
}

// ---------------- cast x -> bf16 (+ zero ctrl counters) ----------------
__global__ __launch_bounds__(256) void cast_f32_to_bf16(
    const float* __restrict__ src, unsigned short* __restrict__ dst, int n4,
    int* __restrict__ ctrl) {
  if (blockIdx.x == 0 && threadIdx.x < 16) ctrl[threadIdx.x] = 0;
  int i = blockIdx.x * blockDim.x + threadIdx.x;
  int stride = gridDim.x * blockDim.x;
  for (; i < n4; i += stride) {
    float4 v = ((const float4*)src)[i];
    u16x4 o;
    o.x = f2bf(v.x); o.y = f2bf(v.y); o.z = f2bf(v.z); o.w = f2bf(v.w);
    ((u16x4*)dst)[i] = o;
  }
}

// ---------------- transpose + cast: src[R][C] f32 -> dst[C][R] bf16 --------
__global__ __launch_bounds__(256) void transpose_cast(
    const float* __restrict__ src, unsigned short* __restrict__ dst,
    int R, int C) {
  __shared__ float tile[32][33];
  size_t base = (size_t)blockIdx.z * R * C;
  int c0 = blockIdx.x * 32, r0 = blockIdx.y * 32;
  for (int i = threadIdx.y; i < 32; i += 8)
    tile[i][threadIdx.x] = src[base + (size_t)(r0 + i) * C + c0 + threadIdx.x];
  __syncthreads();
  for (int i = threadIdx.y; i < 32; i += 8)
    dst[base + (size_t)(c0 + i) * R + r0 + threadIdx.x] = f2bf(tile[threadIdx.x][i]);
}

// ---------------- Wcomb[r][nh*8+e] = sum_d W_mh[r][nh*128+d] * Wr[d][e] ----
__global__ __launch_bounds__(64) void wcomb_kernel(
    const float* __restrict__ Wmh, const float* __restrict__ bmh,
    const float* __restrict__ Wr, float* __restrict__ Wc) {
  int r = blockIdx.x;
  const float* src = (r < 1024) ? (Wmh + (size_t)r * 1024) : bmh;
  int nh = threadIdx.x >> 3, e = threadIdx.x & 7;
  float acc = 0.f;
  for (int d = 0; d < 128; ++d) acc = fmaf(src[nh * 128 + d], Wr[d * 8 + e], acc);
  Wc[(size_t)r * 64 + threadIdx.x] = acc;
}

// ---------------- router: exact fp32 logits, top-2, per-expert counts ------
// grid 512 (8 x-rows each), block 256. Also inits perm/gateb (padding zeros).
__global__ __launch_bounds__(256) void router_kernel(
    const float* __restrict__ x, const float* __restrict__ Wc,
    int* __restrict__ tok_e, float* __restrict__ tok_g,
    int* __restrict__ ctrl, int* __restrict__ perm, float* __restrict__ gateb) {
  int gi = blockIdx.x * 256 + threadIdx.x;
  if (gi < NSLOT) { perm[gi] = 0; gateb[gi] = 0.f; }

  __shared__ float xs[8 * 1024];
  __shared__ float lg[8][64];
  __shared__ int lcnt[8];
  if (threadIdx.x < 8) lcnt[threadIdx.x] = 0;
  int r0 = blockIdx.x * 8;
  const float4* xg = (const float4*)(x + (size_t)r0 * 1024);
  float4* xs4 = (float4*)xs;
  for (int i = threadIdx.x; i < 2048; i += 256) xs4[i] = xg[i];
  __syncthreads();
  int g = threadIdx.x >> 6, lane = threadIdx.x & 63;
  float a0 = Wc[1024 * 64 + lane], a1 = a0;  // bias-combined row
  const float* x0 = xs + g * 1024;
  const float* x1 = xs + (g + 4) * 1024;
  for (int k = 0; k < 1024; ++k) {
    float w = Wc[(size_t)k * 64 + lane];
    a0 = fmaf(x0[k], w, a0);
    a1 = fmaf(x1[k], w, a1);
  }
  lg[g][lane] = a0; lg[g + 4][lane] = a1;
  __syncthreads();
  if (threadIdx.x < 64) {
    int row = threadIdx.x >> 3, nh = threadIdx.x & 7;
    float l[8];
#pragma unroll
    for (int e = 0; e < 8; ++e) l[e] = lg[row][nh * 8 + e];
    int i1 = 0; float v1 = l[0];
#pragma unroll
    for (int e = 1; e < 8; ++e) if (l[e] > v1) { v1 = l[e]; i1 = e; }
    int i2 = -1; float v2 = -1e30f;
#pragma unroll
    for (int e = 0; e < 8; ++e) if (e != i1 && l[e] > v2) { v2 = l[e]; i2 = e; }
    // softmax-then-renormalized-top2 == 2-way softmax over top-2 logits
    float g1 = 1.f / (1.f + __expf(v2 - v1));
    float g2 = 1.f - g1;
    size_t t = (size_t)(r0 + row) * 8 + nh;
    tok_e[t * 2] = i1; tok_e[t * 2 + 1] = i2;
    tok_g[t * 2] = g1; tok_g[t * 2 + 1] = g2;
    atomicAdd(&lcnt[i1], 1);
    atomicAdd(&lcnt[i2], 1);
  }
  __syncthreads();
  if (threadIdx.x < 8 && lcnt[threadIdx.x])
    atomicAdd(&ctrl[CTRL_CNT + threadIdx.x], lcnt[threadIdx.x]);
}

// ---------------- scan: 128-aligned offsets + tile->expert table ----------
__global__ void scan_kernel(int* __restrict__ ctrl) {
  if (threadIdx.x == 0) {
    int off = 0;
    for (int e = 0; e < 8; ++e) {
      ctrl[CTRL_OFF + e] = off;
      off += (ctrl[CTRL_CNT + e] + 127) & ~127;
    }
    ctrl[CTRL_OFF + 8] = off;
    int t = 0;
    for (int e = 0; e < 8; ++e) {
      int tiles = ((ctrl[CTRL_CNT + e] + 127) & ~127) >> 7;
      for (int i = 0; i < tiles; ++i) ctrl[CTRL_TILE + t++] = e;
    }
    for (; t < NTILE_MAX; ++t) ctrl[CTRL_TILE + t] = -1;
  }
}

// ---------------- assign: token -> slot (block-aggregated atomics) --------
__global__ __launch_bounds__(256) void assign_kernel(
    const int* __restrict__ tok_e, const float* __restrict__ tok_g,
    int* __restrict__ ctrl, int* __restrict__ perm,
    float* __restrict__ gateb, int* __restrict__ tok_slot) {
  __shared__ int lcnt[8], lbase[8];
  if (threadIdx.x < 8) lcnt[threadIdx.x] = 0;
  __syncthreads();
  int t = blockIdx.x * 256 + threadIdx.x;
  int e0 = tok_e[t * 2], e1 = tok_e[t * 2 + 1];
  int p0 = atomicAdd(&lcnt[e0], 1);
  int p1 = atomicAdd(&lcnt[e1], 1);
  __syncthreads();
  if (threadIdx.x < 8)
    lbase[threadIdx.x] = atomicAdd(&ctrl[CTRL_CUR + threadIdx.x], lcnt[threadIdx.x]);
  __syncthreads();
  int s0 = ctrl[CTRL_OFF + e0] + lbase[e0] + p0;
  int s1 = ctrl[CTRL_OFF + e1] + lbase[e1] + p1;
  perm[s0] = t; perm[s1] = t;
  gateb[s0] = tok_g[t * 2]; gateb[s1] = tok_g[t * 2 + 1];
  tok_slot[t * 2] = s0; tok_slot[t * 2 + 1] = s1;
}

// ---------------- GEMM: C[M][N] = A[M][K](bf16) @ Bt[N][K](bf16)^T + bias --
template <int OUT_BF16>
__global__ __launch_bounds__(256) void gemm_bt(
    const unsigned short* __restrict__ A, const unsigned short* __restrict__ Bt,
    const float* __restrict__ bias, void* __restrict__ Cout,
    int M, int N, int K) {
  __shared__ unsigned short As[2][128 * 64];
  __shared__ unsigned short Bs[2][128 * 64];
  const int tid = threadIdx.x, lane = tid & 63, wid = tid >> 6;
  const int wr = wid >> 1, wc = wid & 1;
  const int m0 = blockIdx.y * 128, n0 = blockIdx.x * 128;
  const int l15 = lane & 15, lhi = lane >> 4;

  f32x4 acc[4][4];
#pragma unroll
  for (int n = 0; n < 4; ++n) {
    float bv = bias[n0 + wc * 64 + n * 16 + l15];
#pragma unroll
    for (int m = 0; m < 4; ++m) acc[m][n] = (f32x4){bv, bv, bv, bv};
  }

  const int rowi = tid >> 3;
  const int segi = (tid & 7) * 8;
  const int NT = K >> 6;

  auto stage = [&](int buf, int kt) {
    const int k0 = kt * 64;
#pragma unroll
    for (int r = 0; r < 4; ++r) {
      gload_lds16(A + (size_t)(m0 + r * 32 + rowi) * K + k0 + segi,
                  &As[buf][r * 2048 + wid * 512]);
      gload_lds16(Bt + (size_t)(n0 + r * 32 + rowi) * K + k0 + segi,
                  &Bs[buf][r * 2048 + wid * 512]);
    }
  };

  stage(0, 0);
  asm volatile("s_waitcnt vmcnt(0)" ::: "memory");
  __syncthreads();
  int cur = 0;
  for (int t = 0; t < NT; ++t) {
    if (t + 1 < NT) stage(cur ^ 1, t + 1);
#pragma unroll
    for (int ks = 0; ks < 64; ks += 32) {
      bf16x8 af[4], bb[4];
#pragma unroll
      for (int m = 0; m < 4; ++m)
        af[m] = *(const bf16x8*)&As[cur][(wr * 64 + m * 16 + l15) * 64 + ks + lhi * 8];
#pragma unroll
      for (int n = 0; n < 4; ++n)
        bb[n] = *(const bf16x8*)&Bs[cur][(wc * 64 + n * 16 + l15) * 64 + ks + lhi * 8];
#pragma unroll
      for (int m = 0; m < 4; ++m)
#pragma unroll
        for (int n = 0; n < 4; ++n)
          acc[m][n] = __builtin_amdgcn_mfma_f32_16x16x32_bf16(af[m], bb[n], acc[m][n], 0, 0, 0);
    }
    asm volatile("s_waitcnt vmcnt(0)" ::: "memory");
    __syncthreads();
    cur ^= 1;
  }
#pragma unroll
  for (int m = 0; m < 4; ++m) {
#pragma unroll
    for (int n = 0; n < 4; ++n) {
      int col = n0 + wc * 64 + n * 16 + l15;
#pragma unroll
      for (int j = 0; j < 4; ++j) {
        int row = m0 + wr * 64 + m * 16 + lhi * 4 + j;
        if (OUT_BF16)
          ((unsigned short*)Cout)[(size_t)row * N + col] = f2bf(acc[m][n][j]);
        else
          ((float*)Cout)[(size_t)row * N + col] = acc[m][n][j];
      }
    }
  }
}

// ---------------- sparse FFN: one (expert, 128-slot tile) per block --------
// Gathers h rows via perm with pre-swizzled global source; XOR-swizzled LDS
// reads (2-way bank aliasing). y = gate*(gelu(h@W1+b1)@W2 + b2) -> ybuf bf16.
__global__ __launch_bounds__(512) void ffn_sparse_kernel(
    const unsigned short* __restrict__ hbf,   // [32768][128]
    const int* __restrict__ ctrl,
    const int* __restrict__ perm,             // [NSLOT]
    const float* __restrict__ gateb,          // [NSLOT]
    const unsigned short* __restrict__ W1t,   // [8][512][128] (f, hd)
    const float* __restrict__ b1,             // [8][512]
    const unsigned short* __restrict__ W2t,   // [8][128][512] (hd, f)
    const float* __restrict__ b2,             // [8][128]
    unsigned short* __restrict__ ybuf) {      // [NSLOT][128]
  const int e = ctrl[CTRL_TILE + blockIdx.x];
  if (e < 0) return;
  __shared__ unsigned short h_s[128 * 128];
  __shared__ unsigned short act_s[128 * 128];
  __shared__ float g_s[128];
  const int tid = threadIdx.x, lane = tid & 63, wid = tid >> 6;
  const int wr = wid >> 2, wc = wid & 3;
  const int l15 = lane & 15, lhi = lane >> 4;
  const int slot0 = blockIdx.x * 128;

  // gather h rows: linear LDS dest, source pre-swizzled so that swizzled
  // reads (idx ^= (row&7)<<3 on short index) see the logical layout
  for (int s = tid; s < 2048; s += 512) {
    int row = s >> 4, sseg = s & 15;
    int cseg = sseg ^ (row & 7);
    int prow = perm[slot0 + row];
    gload_lds16(hbf + (size_t)prow * 128 + cseg * 8, &h_s[s * 8]);
  }
  if (tid < 128) g_s[tid] = gateb[slot0 + tid];
  asm volatile("s_waitcnt vmcnt(0)" ::: "memory");
  __syncthreads();

  float grow[4][4];
#pragma unroll
  for (int m = 0; m < 4; ++m)
#pragma unroll
    for (int j = 0; j < 4; ++j) grow[m][j] = g_s[wr * 64 + m * 16 + lhi * 4 + j];

  f32x4 yacc[4][2];
#pragma unroll
  for (int m = 0; m < 4; ++m)
#pragma unroll
    for (int n = 0; n < 2; ++n) yacc[m][n] = (f32x4){0.f, 0.f, 0.f, 0.f};

  const unsigned short* W1e = W1t + (size_t)e * 512 * 128;
  const unsigned short* W2e = W2t + (size_t)e * 128 * 512;

  for (int fc = 0; fc < 4; ++fc) {
    f32x4 aacc[4][2];
#pragma unroll
    for (int n = 0; n < 2; ++n) {
      float b1v = b1[(size_t)e * 512 + fc * 128 + wc * 32 + n * 16 + l15];
#pragma unroll
      for (int m = 0; m < 4; ++m) aacc[m][n] = (f32x4){b1v, b1v, b1v, b1v};
    }
    const unsigned short* W1p = W1e + (size_t)fc * 128 * 128;
#pragma unroll
    for (int ks = 0; ks < 128; ks += 32) {
      bf16x8 af[4], bb[2];
#pragma unroll
      for (int m = 0; m < 4; ++m) {
        int row = wr * 64 + m * 16 + l15;
        int col = ks + lhi * 8;
        af[m] = *(const bf16x8*)&h_s[row * 128 + (col ^ ((row & 7) << 3))];
      }
#pragma unroll
      for (int n = 0; n < 2; ++n)
        bb[n] = *(const bf16x8*)(W1p + (size_t)(wc * 32 + n * 16 + l15) * 128 + ks + lhi * 8);
#pragma unroll
      for (int m = 0; m < 4; ++m)
#pragma unroll
        for (int n = 0; n < 2; ++n)
          aacc[m][n] = __builtin_amdgcn_mfma_f32_16x16x32_bf16(af[m], bb[n], aacc[m][n], 0, 0, 0);
    }
    __syncthreads();  // prev fc's act_s reads done
    // gelu(tanh form) * gate -> act_s (swizzled write)
#pragma unroll
    for (int n = 0; n < 2; ++n) {
      int fl = wc * 32 + n * 16 + l15;
#pragma unroll
      for (int m = 0; m < 4; ++m) {
#pragma unroll
        for (int j = 0; j < 4; ++j) {
          int row = wr * 64 + m * 16 + lhi * 4 + j;
          float v = aacc[m][n][j];
          // tanh-gelu: ge = v*(1 - 1/(exp2(v*(c1 + c1*a*v^2)) + 1))
          float s2 = v * v;
          float q = fmaf(0.1029432f, s2, 2.3022078f);
          float E = exp2f(v * q);
          float r = __builtin_amdgcn_rcpf(E + 1.f);
          float ge = fmaf(-v, r, v);
          act_s[row * 128 + (fl ^ ((row & 7) << 3))] = f2bf(ge * grow[m][j]);
        }
      }
    }
    __syncthreads();  // act_s visible
    const unsigned short* W2p = W2e + fc * 128;
#pragma unroll
    for (int ks = 0; ks < 128; ks += 32) {
      bf16x8 af[4], bb[2];
#pragma unroll
      for (int m = 0; m < 4; ++m) {
        int row = wr * 64 + m * 16 + l15;
        int col = ks + lhi * 8;
        af[m] = *(const bf16x8*)&act_s[row * 128 + (col ^ ((row & 7) << 3))];
      }
#pragma unroll
      for (int n = 0; n < 2; ++n)
        bb[n] = *(const bf16x8*)(W2p + (size_t)(wc * 32 + n * 16 + l15) * 512 + ks + lhi * 8);
#pragma unroll
      for (int m = 0; m < 4; ++m)
#pragma unroll
        for (int n = 0; n < 2; ++n)
          yacc[m][n] = __builtin_amdgcn_mfma_f32_16x16x32_bf16(af[m], bb[n], yacc[m][n], 0, 0, 0);
    }
  }
  // epilogue: + gate*b2, write bf16 slots
#pragma unroll
  for (int n = 0; n < 2; ++n) {
    int col = wc * 32 + n * 16 + l15;
    float b2v = b2[(size_t)e * 128 + col];
#pragma unroll
    for (int m = 0; m < 4; ++m) {
#pragma unroll
      for (int j = 0; j < 4; ++j) {
        int row = wr * 64 + m * 16 + lhi * 4 + j;
        float val = fmaf(grow[m][j], b2v, yacc[m][n][j]);
        ybuf[(size_t)(slot0 + row) * 128 + col] = f2bf(val);
      }
    }
  }
}

// ---------------- combine: moe[t] = y[slot0] + y[slot1] -------------------
__global__ __launch_bounds__(256) void combine_kernel(
    const unsigned short* __restrict__ ybuf, const int* __restrict__ tok_slot,
    unsigned short* __restrict__ moebf) {
  int t = blockIdx.x * 8 + (threadIdx.x >> 5);
  int c = (threadIdx.x & 31) * 4;
  int s0 = tok_slot[t * 2], s1 = tok_slot[t * 2 + 1];
  u16x4 a = *(const u16x4*)(ybuf + (size_t)s0 * 128 + c);
  u16x4 b = *(const u16x4*)(ybuf + (size_t)s1 * 128 + c);
  u16x4 o;
#pragma unroll
  for (int i = 0; i < 4; ++i) o[i] = f2bf(bf2f(a[i]) + bf2f(b[i]));
  *(u16x4*)(moebf + (size_t)t * 128 + c) = o;
}

// ---------------------------------------------------------------------------
extern "C" void kernel_launch(void* const* d_in, const int* in_sizes, int n_in,
                              void* d_out, int out_size, void* d_ws, size_t ws_size,
                              hipStream_t stream) {
  const float* x       = (const float*)d_in[0];
  const float* W_mh    = (const float*)d_in[1];
  const float* b_mh    = (const float*)d_in[2];
  const float* W_merge = (const float*)d_in[3];
  const float* b_merge = (const float*)d_in[4];
  const float* W_rout  = (const float*)d_in[5];
  const float* W1      = (const float*)d_in[6];
  const float* b1      = (const float*)d_in[7];
  const float* W2      = (const float*)d_in[8];
  const float* b2      = (const float*)d_in[9];
  float* out = (float*)d_out;

  char* ws = (char*)d_ws;
  size_t off = 0;
  auto alloc = [&](size_t bytes) {
    void* p = ws + off;
    off = (off + bytes + 255) & ~(size_t)255;
    return p;
  };
  unsigned short* x_bf  = (unsigned short*)alloc((size_t)4096 * 1024 * 2);
  unsigned short* Wmh_t = (unsigned short*)alloc((size_t)1024 * 1024 * 2);
  unsigned short* Wmg_t = (unsigned short*)alloc((size_t)1024 * 1024 * 2);
  unsigned short* W1t   = (unsigned short*)alloc((size_t)8 * 512 * 128 * 2);
  unsigned short* W2t   = (unsigned short*)alloc((size_t)8 * 512 * 128 * 2);
  unsigned short* h_bf  = (unsigned short*)alloc((size_t)4096 * 1024 * 2);
  unsigned short* moebf = (unsigned short*)alloc((size_t)4096 * 1024 * 2);
  unsigned short* ybuf  = (unsigned short*)alloc((size_t)NSLOT * 128 * 2);
  float* Wc             = (float*)alloc((size_t)1025 * 64 * 4);
  int*   ctrl           = (int*)alloc(4096);
  int*   tok_e          = (int*)alloc((size_t)32768 * 2 * 4);
  float* tok_g          = (float*)alloc((size_t)32768 * 2 * 4);
  int*   tok_slot       = (int*)alloc((size_t)32768 * 2 * 4);
  int*   perm           = (int*)alloc((size_t)NSLOT * 4);
  float* gateb          = (float*)alloc((size_t)NSLOT * 4);

  cast_f32_to_bf16<<<1024, 256, 0, stream>>>(x, x_bf, 4096 * 1024 / 4, ctrl);
  transpose_cast<<<dim3(32, 32, 1), dim3(32, 8), 0, stream>>>(W_mh, Wmh_t, 1024, 1024);
  transpose_cast<<<dim3(32, 32, 1), dim3(32, 8), 0, stream>>>(W_merge, Wmg_t, 1024, 1024);
  transpose_cast<<<dim3(16, 4, 8), dim3(32, 8), 0, stream>>>(W1, W1t, 128, 512);
  transpose_cast<<<dim3(4, 16, 8), dim3(32, 8), 0, stream>>>(W2, W2t, 512, 128);
  wcomb_kernel<<<1025, 64, 0, stream>>>(W_mh, b_mh, W_rout, Wc);
  router_kernel<<<512, 256, 0, stream>>>(x, Wc, tok_e, tok_g, ctrl, perm, gateb);
  scan_kernel<<<1, 64, 0, stream>>>(ctrl);
  assign_kernel<<<128, 256, 0, stream>>>(tok_e, tok_g, ctrl, perm, gateb, tok_slot);
  gemm_bt<1><<<dim3(8, 32), 256, 0, stream>>>(x_bf, Wmh_t, b_mh, (void*)h_bf, 4096, 1024, 1024);
  ffn_sparse_kernel<<<NTILE_MAX, 512, 0, stream>>>(h_bf, ctrl, perm, gateb, W1t, b1, W2t, b2, ybuf);
  combine_kernel<<<4096, 256, 0, stream>>>(ybuf, tok_slot, moebf);
  gemm_bt<0><<<dim3(8, 32), 256, 0, stream>>>(moebf, Wmg_t, b_merge, (void*)out, 4096, 1024, 1024);
}

// Round 3
// 174.263 us; speedup vs baseline: 2.0018x; 1.2834x over previous
//
#include <hip/hip_runtime.h>

// ---------------------------------------------------------------------------
// MH-MoE, top-2 sparse dispatch, in-register expert FFN (attention-T12 style).
// B=2 S=2048 H=1024 NH=8 HD=128 T=16384 (32768 tokens) E=8 K=2 F=512
// FFN: 32x32x16 MFMA; act stays in registers (cvt_pk_bf16 + permlane32_swap
// repack); weights staged in fragment-linear LDS chunks (conflict-free).
// ---------------------------------------------------------------------------

typedef __attribute__((ext_vector_type(8))) short bf16x8;
typedef __attribute__((ext_vector_type(4))) float f32x4;
typedef __attribute__((ext_vector_type(16))) float f32x16;
typedef __attribute__((ext_vector_type(4))) unsigned short u16x4;

constexpr int NSLOT = 66560;      // 520 tiles * 128 slots
constexpr int NTILE_MAX = 520;
#define CTRL_CNT 0
#define CTRL_CUR 8
#define CTRL_OFF 16
#define CTRL_TILE 32

__device__ __forceinline__ unsigned short f2bf(float x) {
  unsigned int u = __float_as_uint(x);
  return (unsigned short)((u + 0x7FFFu + ((u >> 16) & 1u)) >> 16);
}
__device__ __forceinline__ float bf2f(unsigned short u) {
  return __uint_as_float(((unsigned int)u) << 16);
}
__device__ __forceinline__ void gload_lds16(const void* g, void* l) {
  __builtin_amdgcn_global_load_lds(
      (const __attribute__((address_space(1))) unsigned int*)g,
      (__attribute__((address_space(3))) unsigned int*)l, 16, 0, 0);
}

// ---------------- cast x -> bf16 (+ zero ctrl counters) ----------------
__global__ __launch_bounds__(256) void cast_f32_to_bf16(
    const float* __restrict__ src, unsigned short* __restrict__ dst, int n4,
    int* __restrict__ ctrl) {
  if (blockIdx.x == 0 && threadIdx.x < 16) ctrl[threadIdx.x] = 0;
  int i = blockIdx.x * blockDim.x + threadIdx.x;
  int stride = gridDim.x * blockDim.x;
  for (; i < n4; i += stride) {
    float4 v = ((const float4*)src)[i];
    u16x4 o;
    o.x = f2bf(v.x); o.y = f2bf(v.y); o.z = f2bf(v.z); o.w = f2bf(v.w);
    ((u16x4*)dst)[i] = o;
  }
}

// ---------------- transpose + cast: src[R][C] f32 -> dst[C][R] bf16 --------
__global__ __launch_bounds__(256) void transpose_cast(
    const float* __restrict__ src, unsigned short* __restrict__ dst,
    int R, int C) {
  __shared__ float tile[32][33];
  size_t base = (size_t)blockIdx.z * R * C;
  int c0 = blockIdx.x * 32, r0 = blockIdx.y * 32;
  for (int i = threadIdx.y; i < 32; i += 8)
    tile[i][threadIdx.x] = src[base + (size_t)(r0 + i) * C + c0 + threadIdx.x];
  __syncthreads();
  for (int i = threadIdx.y; i < 32; i += 8)
    dst[base + (size_t)(c0 + i) * R + r0 + threadIdx.x] = f2bf(tile[threadIdx.x][i]);
}

// ---------------- W1 fragment-linear prep ----------------------------------
// W1F[e][ft 16][kk 8][lane 64][j 8] = bf16(W1[e][hd=kk*16+(l>>5)*8+j][f=ft*32+(l&31)])
__global__ __launch_bounds__(64) void w1f_prep(
    const float* __restrict__ W1, unsigned short* __restrict__ W1F) {
  __shared__ float tile[16][32];
  int bid = blockIdx.x;
  int kk = bid & 7, ft = (bid >> 3) & 15, e = bid >> 7;
  const float* src = W1 + (size_t)e * 65536 + (size_t)(kk * 16) * 512 + ft * 32;
  int l = threadIdx.x;
#pragma unroll
  for (int r = 0; r < 8; ++r) {
    int i = l + 64 * r;                 // 0..511
    tile[i >> 5][i & 31] = src[(size_t)(i >> 5) * 512 + (i & 31)];
  }
  __syncthreads();
  int l31 = l & 31, lh = l >> 5;
  bf16x8 v;
#pragma unroll
  for (int j = 0; j < 8; ++j) v[j] = (short)f2bf(tile[lh * 8 + j][l31]);
  *(bf16x8*)(W1F + ((size_t)bid * 64 + l) * 8) = v;
}

// ---------------- W2 fragment-linear prep ----------------------------------
// W2F[e][ft 16][s 2][ht 4][lane 64][j 8] =
//   bf16(W2[e][f=ft*32+s*16+(l>>5)*8+j][hd=ht*32+(l&31)])
__global__ __launch_bounds__(64) void w2f_prep(
    const float* __restrict__ W2, unsigned short* __restrict__ W2F) {
  __shared__ float tile[16][32];
  int bid = blockIdx.x;
  int sht = bid & 7, ft = (bid >> 3) & 15, e = bid >> 7;
  int s = sht >> 2, ht = sht & 3;
  const float* src = W2 + (size_t)e * 65536 + (size_t)(ft * 32 + s * 16) * 128 + ht * 32;
  int l = threadIdx.x;
#pragma unroll
  for (int r = 0; r < 8; ++r) {
    int i = l + 64 * r;
    tile[i >> 5][i & 31] = src[(size_t)(i >> 5) * 128 + (i & 31)];
  }
  __syncthreads();
  int l31 = l & 31, lh = l >> 5;
  bf16x8 v;
#pragma unroll
  for (int j = 0; j < 8; ++j) v[j] = (short)f2bf(tile[lh * 8 + j][l31]);
  *(bf16x8*)(W2F + ((size_t)bid * 64 + l) * 8) = v;
}

// ---------------- Wcomb[r][nh*8+e] = sum_d W_mh[r][nh*128+d] * Wr[d][e] ----
__global__ __launch_bounds__(64) void wcomb_kernel(
    const float* __restrict__ Wmh, const float* __restrict__ bmh,
    const float* __restrict__ Wr, float* __restrict__ Wc) {
  int r = blockIdx.x;
  const float* src = (r < 1024) ? (Wmh + (size_t)r * 1024) : bmh;
  int nh = threadIdx.x >> 3, e = threadIdx.x & 7;
  float acc = 0.f;
  for (int d = 0; d < 128; ++d) acc = fmaf(src[nh * 128 + d], Wr[d * 8 + e], acc);
  Wc[(size_t)r * 64 + threadIdx.x] = acc;
}

// ---------------- router: exact fp32 logits, top-2, per-expert counts ------
__global__ __launch_bounds__(256) void router_kernel(
    const float* __restrict__ x, const float* __restrict__ Wc,
    int* __restrict__ tok_e, float* __restrict__ tok_g,
    int* __restrict__ ctrl, int* __restrict__ perm, float* __restrict__ gateb) {
  int gi = blockIdx.x * 256 + threadIdx.x;
  if (gi < NSLOT) { perm[gi] = 0; gateb[gi] = 0.f; }

  __shared__ float xs[8 * 1024];
  __shared__ float lg[8][64];
  __shared__ int lcnt[8];
  if (threadIdx.x < 8) lcnt[threadIdx.x] = 0;
  int r0 = blockIdx.x * 8;
  const float4* xg = (const float4*)(x + (size_t)r0 * 1024);
  float4* xs4 = (float4*)xs;
  for (int i = threadIdx.x; i < 2048; i += 256) xs4[i] = xg[i];
  __syncthreads();
  int g = threadIdx.x >> 6, lane = threadIdx.x & 63;
  float a0 = Wc[1024 * 64 + lane], a1 = a0;  // bias-combined row
  const float* x0 = xs + g * 1024;
  const float* x1 = xs + (g + 4) * 1024;
  for (int k = 0; k < 1024; ++k) {
    float w = Wc[(size_t)k * 64 + lane];
    a0 = fmaf(x0[k], w, a0);
    a1 = fmaf(x1[k], w, a1);
  }
  lg[g][lane] = a0; lg[g + 4][lane] = a1;
  __syncthreads();
  if (threadIdx.x < 64) {
    int row = threadIdx.x >> 3, nh = threadIdx.x & 7;
    float l[8];
#pragma unroll
    for (int e = 0; e < 8; ++e) l[e] = lg[row][nh * 8 + e];
    int i1 = 0; float v1 = l[0];
#pragma unroll
    for (int e = 1; e < 8; ++e) if (l[e] > v1) { v1 = l[e]; i1 = e; }
    int i2 = -1; float v2 = -1e30f;
#pragma unroll
    for (int e = 0; e < 8; ++e) if (e != i1 && l[e] > v2) { v2 = l[e]; i2 = e; }
    float g1 = 1.f / (1.f + __expf(v2 - v1));
    float g2 = 1.f - g1;
    size_t t = (size_t)(r0 + row) * 8 + nh;
    tok_e[t * 2] = i1; tok_e[t * 2 + 1] = i2;
    tok_g[t * 2] = g1; tok_g[t * 2 + 1] = g2;
    atomicAdd(&lcnt[i1], 1);
    atomicAdd(&lcnt[i2], 1);
  }
  __syncthreads();
  if (threadIdx.x < 8 && lcnt[threadIdx.x])
    atomicAdd(&ctrl[CTRL_CNT + threadIdx.x], lcnt[threadIdx.x]);
}

// ---------------- scan ----------------
__global__ void scan_kernel(int* __restrict__ ctrl) {
  if (threadIdx.x == 0) {
    int off = 0;
    for (int e = 0; e < 8; ++e) {
      ctrl[CTRL_OFF + e] = off;
      off += (ctrl[CTRL_CNT + e] + 127) & ~127;
    }
    ctrl[CTRL_OFF + 8] = off;
    int t = 0;
    for (int e = 0; e < 8; ++e) {
      int tiles = ((ctrl[CTRL_CNT + e] + 127) & ~127) >> 7;
      for (int i = 0; i < tiles; ++i) ctrl[CTRL_TILE + t++] = e;
    }
    for (; t < NTILE_MAX; ++t) ctrl[CTRL_TILE + t] = -1;
  }
}

// ---------------- assign ----------------
__global__ __launch_bounds__(256) void assign_kernel(
    const int* __restrict__ tok_e, const float* __restrict__ tok_g,
    int* __restrict__ ctrl, int* __restrict__ perm,
    float* __restrict__ gateb, int* __restrict__ tok_slot) {
  __shared__ int lcnt[8], lbase[8];
  if (threadIdx.x < 8) lcnt[threadIdx.x] = 0;
  __syncthreads();
  int t = blockIdx.x * 256 + threadIdx.x;
  int e0 = tok_e[t * 2], e1 = tok_e[t * 2 + 1];
  int p0 = atomicAdd(&lcnt[e0], 1);
  int p1 = atomicAdd(&lcnt[e1], 1);
  __syncthreads();
  if (threadIdx.x < 8)
    lbase[threadIdx.x] = atomicAdd(&ctrl[CTRL_CUR + threadIdx.x], lcnt[threadIdx.x]);
  __syncthreads();
  int s0 = ctrl[CTRL_OFF + e0] + lbase[e0] + p0;
  int s1 = ctrl[CTRL_OFF + e1] + lbase[e1] + p1;
  perm[s0] = t; perm[s1] = t;
  gateb[s0] = tok_g[t * 2]; gateb[s1] = tok_g[t * 2 + 1];
  tok_slot[t * 2] = s0; tok_slot[t * 2 + 1] = s1;
}

// ---------------- GEMM: C[M][N] = A[M][K](bf16) @ Bt[N][K](bf16)^T + bias --
// 64x128 tile, BK=64, 4 waves (2 row x 2 col), grid (M/64, N/128)
template <int OUT_BF16>
__global__ __launch_bounds__(256) void gemm_bt(
    const unsigned short* __restrict__ A, const unsigned short* __restrict__ Bt,
    const float* __restrict__ bias, void* __restrict__ Cout,
    int M, int N, int K) {
  __shared__ unsigned short As[2][64 * 64];
  __shared__ unsigned short Bs[2][128 * 64];
  const int tid = threadIdx.x, lane = tid & 63, wid = tid >> 6;
  const int wr = wid & 1, wc = wid >> 1;
  const int m0 = blockIdx.x * 64, n0 = blockIdx.y * 128;
  const int l15 = lane & 15, lhi = lane >> 4;

  f32x4 acc[2][4];
#pragma unroll
  for (int n = 0; n < 4; ++n) {
    float bv = bias[n0 + wc * 64 + n * 16 + l15];
#pragma unroll
    for (int m = 0; m < 2; ++m) acc[m][n] = (f32x4){bv, bv, bv, bv};
  }

  const int rowi = tid >> 3;       // 0..31
  const int segi = (tid & 7) * 8;  // k offset
  const int NT = K >> 6;

  auto stage = [&](int buf, int kt) {
    const int k0 = kt * 64;
#pragma unroll
    for (int r = 0; r < 2; ++r)
      gload_lds16(A + (size_t)(m0 + r * 32 + rowi) * K + k0 + segi,
                  &As[buf][r * 2048 + wid * 512]);
#pragma unroll
    for (int r = 0; r < 4; ++r)
      gload_lds16(Bt + (size_t)(n0 + r * 32 + rowi) * K + k0 + segi,
                  &Bs[buf][r * 2048 + wid * 512]);
  };

  stage(0, 0);
  asm volatile("s_waitcnt vmcnt(0)" ::: "memory");
  __syncthreads();
  int cur = 0;
  for (int t = 0; t < NT; ++t) {
    if (t + 1 < NT) stage(cur ^ 1, t + 1);
#pragma unroll
    for (int ks = 0; ks < 64; ks += 32) {
      bf16x8 af[2], bb[4];
#pragma unroll
      for (int m = 0; m < 2; ++m)
        af[m] = *(const bf16x8*)&As[cur][(wr * 32 + m * 16 + l15) * 64 + ks + lhi * 8];
#pragma unroll
      for (int n = 0; n < 4; ++n)
        bb[n] = *(const bf16x8*)&Bs[cur][(wc * 64 + n * 16 + l15) * 64 + ks + lhi * 8];
#pragma unroll
      for (int m = 0; m < 2; ++m)
#pragma unroll
        for (int n = 0; n < 4; ++n)
          acc[m][n] = __builtin_amdgcn_mfma_f32_16x16x32_bf16(af[m], bb[n], acc[m][n], 0, 0, 0);
    }
    asm volatile("s_waitcnt vmcnt(0)" ::: "memory");
    __syncthreads();
    cur ^= 1;
  }
#pragma unroll
  for (int m = 0; m < 2; ++m) {
#pragma unroll
    for (int n = 0; n < 4; ++n) {
      int col = n0 + wc * 64 + n * 16 + l15;
#pragma unroll
      for (int j = 0; j < 4; ++j) {
        int row = m0 + wr * 32 + m * 16 + lhi * 4 + j;
        if (OUT_BF16)
          ((unsigned short*)Cout)[(size_t)row * N + col] = f2bf(acc[m][n][j]);
        else
          ((float*)Cout)[(size_t)row * N + col] = acc[m][n][j];
      }
    }
  }
}

// ---------------- sparse FFN v3: in-register act, 32x32x16 MFMA ------------
// Block: 128 slots, 4 waves (32 slots each). Per f-tile (32 f):
//   aacc[f][tok] = mfma(W1frag, hfrag) + b1 ; gelu*gate in-register ;
//   cvt_pk + permlane32_swap -> act B-frags ; yacc[ht] += mfma(W2frag, act).
// Weights stream through fragment-linear LDS (double-buffered, conflict-free).
__global__ __launch_bounds__(256, 2) void ffn_sparse_v3(
    const unsigned short* __restrict__ hbf,   // [32768][128]
    const int* __restrict__ ctrl,
    const int* __restrict__ perm,             // [NSLOT]
    const float* __restrict__ gateb,          // [NSLOT]
    const unsigned short* __restrict__ W1F,   // [e][16][8][64][8]
    const float* __restrict__ b1,             // [8][512]
    const unsigned short* __restrict__ W2F,   // [e][16][2][4][64][8]
    const float* __restrict__ b2,             // [8][128]
    unsigned short* __restrict__ ybuf) {      // [NSLOT][128]
  const int e = ctrl[CTRL_TILE + blockIdx.x];
  if (e < 0) return;
  __shared__ unsigned short W1c[2][4096];
  __shared__ unsigned short W2c[2][4096];
  __shared__ float b1_s[512];
  __shared__ float b2_s[128];
  const int tid = threadIdx.x, l = tid & 63, w = tid >> 6;
  const int l31 = l & 31, lh = l >> 5;
  const int slot = blockIdx.x * 128 + w * 32 + l31;
  const int prow = perm[slot];
  const float gate = gateb[slot];

  // h B-fragments: col=tok(l31), k=hd = kk*16 + lh*8 + j  (held all kernel)
  bf16x8 hreg[8];
  const unsigned short* hsrc = hbf + (size_t)prow * 128 + lh * 8;
#pragma unroll
  for (int kk = 0; kk < 8; ++kk)
    hreg[kk] = *(const bf16x8*)(hsrc + kk * 16);

  if (tid < 128) ((float4*)b1_s)[tid] = ((const float4*)(b1 + e * 512))[tid];
  if (tid < 32)  ((float4*)b2_s)[tid] = ((const float4*)(b2 + e * 128))[tid];

  const unsigned short* W1e = W1F + (size_t)e * 65536;
  const unsigned short* W2e = W2F + (size_t)e * 65536;
  auto stage = [&](int buf, int ft) {
#pragma unroll
    for (int r = 0; r < 2; ++r) {
      gload_lds16(W1e + (size_t)ft * 4096 + (size_t)(r * 256 + tid) * 8,
                  &W1c[buf][r * 2048 + w * 512]);
      gload_lds16(W2e + (size_t)ft * 4096 + (size_t)(r * 256 + tid) * 8,
                  &W2c[buf][r * 2048 + w * 512]);
    }
  };

  stage(0, 0);
  asm volatile("s_waitcnt vmcnt(0)" ::: "memory");
  __syncthreads();

  f32x16 yacc[4] = {};
  int cur = 0;
  for (int ft = 0; ft < 16; ++ft) {
    if (ft < 15) stage(cur ^ 1, ft + 1);
    // aacc init = b1 (rows: f = ft*32 + (reg&3) + 8*(reg>>2) + 4*lh)
    const float4* b14 = (const float4*)b1_s;
    float4 q0 = b14[ft * 8 + lh];
    float4 q1 = b14[ft * 8 + lh + 2];
    float4 q2 = b14[ft * 8 + lh + 4];
    float4 q3 = b14[ft * 8 + lh + 6];
    f32x16 aacc = {q0.x, q0.y, q0.z, q0.w, q1.x, q1.y, q1.z, q1.w,
                   q2.x, q2.y, q2.z, q2.w, q3.x, q3.y, q3.z, q3.w};
#pragma unroll
    for (int kk = 0; kk < 8; ++kk) {
      bf16x8 a1 = *(const bf16x8*)&W1c[cur][(kk * 64 + l) * 8];
      aacc = __builtin_amdgcn_mfma_f32_32x32x16_bf16(a1, hreg[kk], aacc, 0, 0, 0);
    }
    // gelu(tanh) * gate, in-register
    float ge[16];
#pragma unroll
    for (int r = 0; r < 16; ++r) {
      float v = aacc[r];
      float s2 = v * v;
      float q = fmaf(0.1029432f, s2, 2.3022078f);
      float E = exp2f(v * q);
      float rc = __builtin_amdgcn_rcpf(E + 1.f);
      ge[r] = fmaf(-v, rc, v) * gate;
    }
    // pack pairs -> bf16 words; swap halves to form B-frags (k = f)
    unsigned pk[8];
#pragma unroll
    for (int p = 0; p < 8; ++p) {
      unsigned r;
      asm("v_cvt_pk_bf16_f32 %0, %1, %2" : "=v"(r) : "v"(ge[2 * p]), "v"(ge[2 * p + 1]));
      pk[p] = r;
    }
    asm volatile("v_permlane32_swap_b32 %0, %1" : "+v"(pk[0]), "+v"(pk[2]));
    asm volatile("v_permlane32_swap_b32 %0, %1" : "+v"(pk[1]), "+v"(pk[3]));
    asm volatile("v_permlane32_swap_b32 %0, %1" : "+v"(pk[4]), "+v"(pk[6]));
    asm volatile("v_permlane32_swap_b32 %0, %1" : "+v"(pk[5]), "+v"(pk[7]));
    typedef __attribute__((ext_vector_type(4))) unsigned u32x4;
    u32x4 f0 = {pk[0], pk[1], pk[2], pk[3]};
    u32x4 f1 = {pk[4], pk[5], pk[6], pk[7]};
    bf16x8 act0 = __builtin_bit_cast(bf16x8, f0);
    bf16x8 act1 = __builtin_bit_cast(bf16x8, f1);
    // phase 2: yacc[ht] += W2frag @ act
#pragma unroll
    for (int ht = 0; ht < 4; ++ht) {
      bf16x8 a20 = *(const bf16x8*)&W2c[cur][((0 * 4 + ht) * 64 + l) * 8];
      yacc[ht] = __builtin_amdgcn_mfma_f32_32x32x16_bf16(a20, act0, yacc[ht], 0, 0, 0);
      bf16x8 a21 = *(const bf16x8*)&W2c[cur][((1 * 4 + ht) * 64 + l) * 8];
      yacc[ht] = __builtin_amdgcn_mfma_f32_32x32x16_bf16(a21, act1, yacc[ht], 0, 0, 0);
    }
    asm volatile("s_waitcnt vmcnt(0)" ::: "memory");
    __syncthreads();
    cur ^= 1;
  }
  // epilogue: y + gate*b2 -> bf16 pairs -> 4B stores (col = own token)
#pragma unroll
  for (int ht = 0; ht < 4; ++ht) {
#pragma unroll
    for (int rp = 0; rp < 8; ++rp) {
      int fr = ((2 * rp) & 3) + 8 * (rp >> 1) + 4 * lh;
      int hd = ht * 32 + fr;
      float2 bb2 = *(const float2*)&b2_s[hd];
      float v0 = fmaf(gate, bb2.x, yacc[ht][2 * rp]);
      float v1 = fmaf(gate, bb2.y, yacc[ht][2 * rp + 1]);
      unsigned pw;
      asm("v_cvt_pk_bf16_f32 %0, %1, %2" : "=v"(pw) : "v"(v0), "v"(v1));
      *(unsigned*)(ybuf + (size_t)slot * 128 + hd) = pw;
    }
  }
}

// ---------------- combine: moe[t] = y[slot0] + y[slot1] -------------------
__global__ __launch_bounds__(256) void combine_kernel(
    const unsigned short* __restrict__ ybuf, const int* __restrict__ tok_slot,
    unsigned short* __restrict__ moebf) {
  int t = blockIdx.x * 8 + (threadIdx.x >> 5);
  int c = (threadIdx.x & 31) * 4;
  int s0 = tok_slot[t * 2], s1 = tok_slot[t * 2 + 1];
  u16x4 a = *(const u16x4*)(ybuf + (size_t)s0 * 128 + c);
  u16x4 b = *(const u16x4*)(ybuf + (size_t)s1 * 128 + c);
  u16x4 o;
#pragma unroll
  for (int i = 0; i < 4; ++i) o[i] = f2bf(bf2f(a[i]) + bf2f(b[i]));
  *(u16x4*)(moebf + (size_t)t * 128 + c) = o;
}

// ---------------------------------------------------------------------------
extern "C" void kernel_launch(void* const* d_in, const int* in_sizes, int n_in,
                              void* d_out, int out_size, void* d_ws, size_t ws_size,
                              hipStream_t stream) {
  const float* x       = (const float*)d_in[0];
  const float* W_mh    = (const float*)d_in[1];
  const float* b_mh    = (const float*)d_in[2];
  const float* W_merge = (const float*)d_in[3];
  const float* b_merge = (const float*)d_in[4];
  const float* W_rout  = (const float*)d_in[5];
  const float* W1      = (const float*)d_in[6];
  const float* b1      = (const float*)d_in[7];
  const float* W2      = (const float*)d_in[8];
  const float* b2      = (const float*)d_in[9];
  float* out = (float*)d_out;

  char* ws = (char*)d_ws;
  size_t off = 0;
  auto alloc = [&](size_t bytes) {
    void* p = ws + off;
    off = (off + bytes + 255) & ~(size_t)255;
    return p;
  };
  unsigned short* x_bf  = (unsigned short*)alloc((size_t)4096 * 1024 * 2);
  unsigned short* Wmh_t = (unsigned short*)alloc((size_t)1024 * 1024 * 2);
  unsigned short* Wmg_t = (unsigned short*)alloc((size_t)1024 * 1024 * 2);
  unsigned short* W1F   = (unsigned short*)alloc((size_t)8 * 512 * 128 * 2);
  unsigned short* W2F   = (unsigned short*)alloc((size_t)8 * 512 * 128 * 2);
  unsigned short* h_bf  = (unsigned short*)alloc((size_t)4096 * 1024 * 2);
  unsigned short* moebf = (unsigned short*)alloc((size_t)4096 * 1024 * 2);
  unsigned short* ybuf  = (unsigned short*)alloc((size_t)NSLOT * 128 * 2);
  float* Wc             = (float*)alloc((size_t)1025 * 64 * 4);
  int*   ctrl           = (int*)alloc(4096);
  int*   tok_e          = (int*)alloc((size_t)32768 * 2 * 4);
  float* tok_g          = (float*)alloc((size_t)32768 * 2 * 4);
  int*   tok_slot       = (int*)alloc((size_t)32768 * 2 * 4);
  int*   perm           = (int*)alloc((size_t)NSLOT * 4);
  float* gateb          = (float*)alloc((size_t)NSLOT * 4);

  cast_f32_to_bf16<<<1024, 256, 0, stream>>>(x, x_bf, 4096 * 1024 / 4, ctrl);
  transpose_cast<<<dim3(32, 32, 1), dim3(32, 8), 0, stream>>>(W_mh, Wmh_t, 1024, 1024);
  transpose_cast<<<dim3(32, 32, 1), dim3(32, 8), 0, stream>>>(W_merge, Wmg_t, 1024, 1024);
  w1f_prep<<<1024, 64, 0, stream>>>(W1, W1F);
  w2f_prep<<<1024, 64, 0, stream>>>(W2, W2F);
  wcomb_kernel<<<1025, 64, 0, stream>>>(W_mh, b_mh, W_rout, Wc);
  router_kernel<<<512, 256, 0, stream>>>(x, Wc, tok_e, tok_g, ctrl, perm, gateb);
  scan_kernel<<<1, 64, 0, stream>>>(ctrl);
  assign_kernel<<<128, 256, 0, stream>>>(tok_e, tok_g, ctrl, perm, gateb, tok_slot);
  gemm_bt<1><<<dim3(64, 8), 256, 0, stream>>>(x_bf, Wmh_t, b_mh, (void*)h_bf, 4096, 1024, 1024);
  ffn_sparse_v3<<<NTILE_MAX, 256, 0, stream>>>(h_bf, ctrl, perm, gateb, W1F, b1, W2F, b2, ybuf);
  combine_kernel<<<4096, 256, 0, stream>>>(ybuf, tok_slot, moebf);
  gemm_bt<0><<<dim3(64, 8), 256, 0, stream>>>(moebf, Wmg_t, b_merge, (void*)out, 4096, 1024, 1024);
}